// Round 4
// baseline (361.500 us; speedup 1.0000x reference)
//
#include <hip/hip_runtime.h>
#include <math.h>

#define B_ 32
#define Q_ 16
#define D_ 10
#define L_ 1000
#define E_ 300
#define NC 75           // float4 chunks per row
#define RT 250          // rows per block (4 l-splits)
#define NG 19           // 4-chunk groups (last group has 3 valid chunks)
#define PL 1040         // LDS plane stride in dwords (256 rows*4 + 16 pad)
#define BUFSZ (4*PL)    // one double-buffer half: 4 chunk-planes

// ---------------------------------------------------------------------------
// Kernel 1 (prep): gate logits -> softmax -> fused per-query weight
//   wq[b,q]    = softmax(gate_logits)[b,q] * out_w * w2
//   invNq[b,q] = 1/||emb[q_tok]||
//   score[b,d] = out_w*(w2*b1 + b2) + out_b   (atomics add onto this)
// ---------------------------------------------------------------------------
__global__ __launch_bounds__(256) void drmm_prep(
    const int* __restrict__ bq, const float* __restrict__ emb,
    const float* __restrict__ gate_w, const float* __restrict__ gate_b,
    const float* __restrict__ b1, const float* __restrict__ w2,
    const float* __restrict__ b2, const float* __restrict__ out_w,
    const float* __restrict__ out_b,
    float* __restrict__ wqBuf, float* __restrict__ invNqBuf,
    float* __restrict__ score)
{
    const int b = blockIdx.x;
    const int tid = threadIdx.x;
    const int w = tid >> 6, lane = tid & 63;
    __shared__ float logits[Q_];

#pragma unroll
    for (int i = 0; i < 4; ++i) {
        const int q = w * 4 + i;
        const int tok = bq[b * Q_ + q];
        const float* row = emb + (size_t)tok * E_;
        float4 dv = *(const float4*)(row + 4 * lane);
        float4 gv = *(const float4*)(gate_w + 4 * lane);
        float pd = dv.x * gv.x + dv.y * gv.y + dv.z * gv.z + dv.w * gv.w;
        float ps = dv.x * dv.x + dv.y * dv.y + dv.z * dv.z + dv.w * dv.w;
        if (lane < 11) {
            float4 dv2 = *(const float4*)(row + 256 + 4 * lane);
            float4 gv2 = *(const float4*)(gate_w + 256 + 4 * lane);
            pd += dv2.x * gv2.x + dv2.y * gv2.y + dv2.z * gv2.z + dv2.w * gv2.w;
            ps += dv2.x * dv2.x + dv2.y * dv2.y + dv2.z * dv2.z + dv2.w * dv2.w;
        }
#pragma unroll
        for (int off = 32; off > 0; off >>= 1) {
            pd += __shfl_xor(pd, off);
            ps += __shfl_xor(ps, off);
        }
        if (lane == 0) {
            logits[q] = pd + gate_b[0];
            invNqBuf[b * Q_ + q] = 1.0f / sqrtf(ps);
        }
    }
    __syncthreads();

    if (tid == 0) {
        float m = -1e30f;
        for (int q = 0; q < Q_; ++q) m = fmaxf(m, logits[q]);
        float e[Q_];
        float s = 0.f;
        for (int q = 0; q < Q_; ++q) { e[q] = expf(logits[q] - m); s += e[q]; }
        const float sc = out_w[0] * w2[0] / s;
        for (int q = 0; q < Q_; ++q) wqBuf[b * Q_ + q] = e[q] * sc;
    }
    if (tid < D_)
        score[b * D_ + tid] = out_w[0] * (w2[0] * b1[0] + b2[0]) + out_b[0];
}

// ---------------------------------------------------------------------------
// Kernel 2 (main): coalesced gather -> LDS transpose -> row-per-lane compute.
//  Per 4-chunk group:
//   load:  thread t fetches chunk 4j+(t&3) of rows {64m + t>>2} (m=0..3)
//          -> 64 B contiguous per row-quad (coalesced), each line touched once
//   stage: chunk-major LDS planes, stride 1040 dw -> conflict-free both ways
//   compute: lane t = row t reads its float4 back (ds_read_b128) and runs
//          16 uniform q-chunks via s_load_dwordx4 (scalar pipe) + 68 FMA
//  Double-buffered tile, one barrier per group, prefetch spans the barrier.
// ---------------------------------------------------------------------------
__global__ __launch_bounds__(256) void drmm_main(
    const int* __restrict__ bq, const int* __restrict__ bdocs,
    const float* __restrict__ emb, const float* __restrict__ w1,
    const float* __restrict__ wqBuf, const float* __restrict__ invNqBuf,
    float* __restrict__ score)
{
    const int ls = blockIdx.x;   // l-split 0..3 (250 rows each)
    const int d  = blockIdx.y;
    const int b  = blockIdx.z;
    const int t  = threadIdx.x;

    __shared__ float lds[2 * BUFSZ];   // 33.3 KB doc tile (double-buffered)
    __shared__ int   toks[256];
    __shared__ float wsum[4];

    // doc tokens for this block's rows (250..255 clamp; results discarded)
    {
        const int r = (t < RT) ? t : (RT - 1);
        toks[t] = bdocs[(b * D_ + d) * L_ + ls * RT + r];
    }
    __syncthreads();

    int qtok[Q_];
#pragma unroll
    for (int q = 0; q < Q_; ++q) qtok[q] = bq[b * Q_ + q];   // uniform -> SGPR

    float acc[Q_];
#pragma unroll
    for (int q = 0; q < Q_; ++q) acc[q] = 0.f;
    float sq = 0.f;

    const int cc = t & 3;    // chunk-within-group this thread stages
    const int rr = t >> 2;   // row offset 0..63 (batches add 64m)

    float4 st[4];
#pragma unroll
    for (int m = 0; m < 4; ++m)        // prefetch group 0 (chunk cc < 75)
        st[m] = *(const float4*)(emb + (size_t)toks[64 * m + rr] * E_ + 4 * cc);

#pragma unroll 1
    for (int j = 0; j < NG; ++j) {
        float* bufp = lds + (j & 1) * BUFSZ;
        // stage group j (bank-even writes, 8 dw/bank = b128 minimum)
#pragma unroll
        for (int m = 0; m < 4; ++m)
            *(float4*)(bufp + cc * PL + (64 * m + rr) * 4) = st[m];
        // prefetch group j+1 (latency spans barrier + compute)
        if (j < NG - 1) {
            int c = 4 * (j + 1) + cc;
            if (c > NC - 1) c = NC - 1;          // only j==17->18, t&3==3
#pragma unroll
            for (int m = 0; m < 4; ++m)
                st[m] = *(const float4*)(emb + (size_t)toks[64 * m + rr] * E_ + 4 * c);
        }
        __syncthreads();   // also separates these writes from reads of j-1

        // compute group j: lane t = row t
#pragma unroll
        for (int c = 0; c < 4; ++c) {
            const int chunk = 4 * j + c;
            if (chunk < NC) {                    // uniform branch
                const float4 dv = *(const float4*)(bufp + c * PL + t * 4);
                sq = fmaf(dv.x, dv.x, fmaf(dv.y, dv.y,
                     fmaf(dv.z, dv.z, fmaf(dv.w, dv.w, sq))));
#pragma unroll
                for (int q = 0; q < Q_; ++q) {
                    const float4 qv = *(const float4*)
                        (emb + (size_t)qtok[q] * E_ + 4 * chunk); // s_load_dwordx4
                    acc[q] = fmaf(dv.w, qv.w, fmaf(dv.z, qv.z,
                             fmaf(dv.y, qv.y, fmaf(dv.x, qv.x, acc[q]))));
                }
            }
        }
    }

    // epilogue: bin + weight (rows >= 250 are clamped duplicates -> drop)
    float total = 0.f;
    if (t < RT) {
        const float nd = sqrtf(sq);
        const float w10 = w1[0], w11 = w1[1], w12 = w1[2], w13 = w1[3], w14 = w1[4];
#pragma unroll
        for (int q = 0; q < Q_; ++q) {
            const float a = acc[q] * invNqBuf[b * Q_ + q];  // = dot/||q||
            const float wv = (a < -nd)        ? 0.f
                           : (a < -0.5f * nd) ? w10
                           : (a < 0.f)        ? w11
                           : (a < 0.5f * nd)  ? w12
                           : (a < nd)         ? w13
                           : (a <= nd)        ? w14
                                              : 0.f;
            total = fmaf(wqBuf[b * Q_ + q], wv, total);     // uniform s_loads
        }
    }
#pragma unroll
    for (int off = 32; off > 0; off >>= 1) total += __shfl_xor(total, off);
    if ((t & 63) == 0) wsum[t >> 6] = total;
    __syncthreads();
    if (t == 0)
        atomicAdd(&score[b * D_ + d], wsum[0] + wsum[1] + wsum[2] + wsum[3]);
}

extern "C" void kernel_launch(void* const* d_in, const int* in_sizes, int n_in,
                              void* d_out, int out_size, void* d_ws, size_t ws_size,
                              hipStream_t stream)
{
    const int*   bq     = (const int*)d_in[0];
    const int*   bdocs  = (const int*)d_in[1];
    const float* emb    = (const float*)d_in[2];
    const float* gate_w = (const float*)d_in[3];
    const float* gate_b = (const float*)d_in[4];
    const float* w1     = (const float*)d_in[5];
    const float* b1     = (const float*)d_in[6];
    const float* w2     = (const float*)d_in[7];
    const float* b2     = (const float*)d_in[8];
    const float* out_w  = (const float*)d_in[9];
    const float* out_b  = (const float*)d_in[10];

    float* score  = (float*)d_out;
    float* wqBuf  = (float*)d_ws;          // 512 floats
    float* invNq  = wqBuf + B_ * Q_;       // 512 floats  (ws usage: 4 KiB)

    drmm_prep<<<dim3(B_), dim3(256), 0, stream>>>(
        bq, emb, gate_w, gate_b, b1, w2, b2, out_w, out_b, wqBuf, invNq, score);

    drmm_main<<<dim3(4, D_, B_), dim3(256), 0, stream>>>(
        bq, bdocs, emb, w1, wqBuf, invNq, score);
}

// Round 5
// 263.483 us; speedup vs baseline: 1.3720x; 1.3720x over previous
//
#include <hip/hip_runtime.h>
#include <math.h>

#define B_ 32
#define Q_ 16
#define D_ 10
#define L_ 1000
#define E_ 300
#define NCH 75          // float4 chunks per row
#define NGRP 19         // 4-chunk groups (last has 3 valid)

// ---------------------------------------------------------------------------
// Kernel 1 (prep): gate logits -> softmax -> fused per-query weight
//   wq[b,q]    = softmax(gate_logits)[b,q] * out_w * w2
//   invNq[b,q] = 1/||emb[q_tok]||
//   score[b,d] = out_w*(w2*b1 + b2) + out_b   (atomics add onto this)
// ---------------------------------------------------------------------------
__global__ __launch_bounds__(256) void drmm_prep(
    const int* __restrict__ bq, const float* __restrict__ emb,
    const float* __restrict__ gate_w, const float* __restrict__ gate_b,
    const float* __restrict__ b1, const float* __restrict__ w2,
    const float* __restrict__ b2, const float* __restrict__ out_w,
    const float* __restrict__ out_b,
    float* __restrict__ wqBuf, float* __restrict__ invNqBuf,
    float* __restrict__ score)
{
    const int b = blockIdx.x;
    const int tid = threadIdx.x;
    const int w = tid >> 6, lane = tid & 63;
    __shared__ float logits[Q_];

#pragma unroll
    for (int i = 0; i < 4; ++i) {
        const int q = w * 4 + i;
        const int tok = bq[b * Q_ + q];
        const float* row = emb + (size_t)tok * E_;
        float4 dv = *(const float4*)(row + 4 * lane);
        float4 gv = *(const float4*)(gate_w + 4 * lane);
        float pd = dv.x * gv.x + dv.y * gv.y + dv.z * gv.z + dv.w * gv.w;
        float ps = dv.x * dv.x + dv.y * dv.y + dv.z * dv.z + dv.w * dv.w;
        if (lane < 11) {
            float4 dv2 = *(const float4*)(row + 256 + 4 * lane);
            float4 gv2 = *(const float4*)(gate_w + 256 + 4 * lane);
            pd += dv2.x * gv2.x + dv2.y * gv2.y + dv2.z * gv2.z + dv2.w * gv2.w;
            ps += dv2.x * dv2.x + dv2.y * dv2.y + dv2.z * dv2.z + dv2.w * dv2.w;
        }
#pragma unroll
        for (int off = 32; off > 0; off >>= 1) {
            pd += __shfl_xor(pd, off);
            ps += __shfl_xor(ps, off);
        }
        if (lane == 0) {
            logits[q] = pd + gate_b[0];
            invNqBuf[b * Q_ + q] = 1.0f / sqrtf(ps);
        }
    }
    __syncthreads();

    if (tid == 0) {
        float m = -1e30f;
        for (int q = 0; q < Q_; ++q) m = fmaxf(m, logits[q]);
        float e[Q_];
        float s = 0.f;
        for (int q = 0; q < Q_; ++q) { e[q] = expf(logits[q] - m); s += e[q]; }
        const float sc = out_w[0] * w2[0] / s;
        for (int q = 0; q < Q_; ++q) wqBuf[b * Q_ + q] = e[q] * sc;
    }
    if (tid < D_)
        score[b * D_ + tid] = out_w[0] * (w2[0] * b1[0] + b2[0]) + out_b[0];
}

// ---------------------------------------------------------------------------
// Kernel 2 (main): wave-private coalesced gather -> LDS transpose (NO block
// barrier in the loop) -> row-per-lane compute with q broadcast from LDS.
//  - wave owns 64 rows; per 4-chunk group, lane l loads chunk (l&3) of rows
//    (l>>2)+16m  -> 64 B contiguous per row-quad, 16 line-reqs per wave-load
//  - wave-private double-buffered tile, row stride 5 float4 (+1 pad) ->
//    both write (5r+c)%8 and read (5l+c)%8 patterns are uniform 8/quad
//  - intra-wave DS is in-order in HW; __builtin_amdgcn_wave_barrier() pins
//    compiler ordering between transpose writes and readback
//  - q tile (75x16 float4, 19.2 KB) staged once; per-chunk q reads are
//    same-address ds_read_b128 broadcasts (replaces R3's K$-thrashing s_loads)
// ---------------------------------------------------------------------------
__global__ __launch_bounds__(256) void drmm_main(
    const int* __restrict__ bq, const int* __restrict__ bdocs,
    const float* __restrict__ emb, const float* __restrict__ w1,
    const float* __restrict__ wqBuf, const float* __restrict__ invNqBuf,
    float* __restrict__ score)
{
    const int ls = blockIdx.x;   // l-split 0..3 (250 rows each)
    const int d  = blockIdx.y;
    const int b  = blockIdx.z;
    const int t  = threadIdx.x;
    const int w  = t >> 6, l = t & 63;

    __shared__ float4 qtile[NCH * Q_];      // [chunk*16+q], 19.2 KB
    __shared__ float4 dtile[4][2][320];     // per-wave double buffer, 40 KB
    __shared__ float  wsum[4];

    // ---- stage q tile once (coalesced: 16 consecutive threads per q-row)
    {
        const int q = t >> 4, c0 = t & 15;
        const float* qr = emb + (size_t)bq[b * Q_ + q] * E_;
#pragma unroll
        for (int k = 0; k < 5; ++k) {
            const int c = c0 + 16 * k;
            if (c < NCH) qtile[c * Q_ + q] = *(const float4*)(qr + 4 * c);
        }
    }

    // own doc token (rows 250..255 clamp; dropped in epilogue)
    const int mytok = bdocs[(b * D_ + d) * L_ + ls * 250 + ((t < 250) ? t : 249)];
    __syncthreads();   // qtile ready (only block-wide barrier before epilogue)

    // staging bases: lane l loads chunk (l&3) of wave-rows (l>>2)+16m
    const float* base[4];
#pragma unroll
    for (int m = 0; m < 4; ++m) {
        const int tk = __shfl(mytok, (l >> 2) + 16 * m);
        base[m] = emb + (size_t)tk * E_ + (l & 3) * 4;
    }

    float acc[Q_];
#pragma unroll
    for (int q = 0; q < Q_; ++q) acc[q] = 0.f;
    float sq = 0.f;

    float4 st[4];
#pragma unroll
    for (int m = 0; m < 4; ++m) st[m] = *(const float4*)(base[m]);  // group 0

    float4* const buf0 = &dtile[w][0][0];
    float4* const buf1 = &dtile[w][1][0];
    const int wslot = 5 * (l >> 2) + (l & 3);   // + 80*m per m

#pragma unroll 1
    for (int j = 0; j < NGRP; ++j) {
        float4* bp = (j & 1) ? buf1 : buf0;
        // transpose-write group j (uniform 8 lanes/bank-quad -> conflict-free)
#pragma unroll
        for (int m = 0; m < 4; ++m) bp[wslot + 80 * m] = st[m];
        // prefetch group j+1 (global latency spans this group's compute)
        if (j < NGRP - 1) {
            int foff = 16 * (j + 1);
            if (4 * (j + 1) + (l & 3) > NCH - 1) foff -= 4;  // last-group clamp
#pragma unroll
            for (int m = 0; m < 4; ++m) st[m] = *(const float4*)(base[m] + foff);
        }
        __builtin_amdgcn_wave_barrier();   // order writes before reads (HW DS in-order)
        // compute group j: lane l = wave-row l
#pragma unroll
        for (int c = 0; c < 4; ++c) {
            const int chunk = 4 * j + c;
            if (chunk < NCH) {                       // uniform branch
                const float4 dv = bp[5 * l + c];
                sq = fmaf(dv.x, dv.x, fmaf(dv.y, dv.y,
                     fmaf(dv.z, dv.z, fmaf(dv.w, dv.w, sq))));
#pragma unroll
                for (int q = 0; q < Q_; ++q) {
                    const float4 qv = qtile[chunk * Q_ + q];   // broadcast read
                    acc[q] = fmaf(dv.w, qv.w, fmaf(dv.z, qv.z,
                             fmaf(dv.y, qv.y, fmaf(dv.x, qv.x, acc[q]))));
                }
            }
        }
        __builtin_amdgcn_wave_barrier();   // keep reads of j before writes of j+2
    }

    // epilogue: bin + weight (identical arithmetic/order to R3)
    float total = 0.f;
    if (t < 250) {
        const float nd = sqrtf(sq);
        const float w10 = w1[0], w11 = w1[1], w12 = w1[2], w13 = w1[3], w14 = w1[4];
#pragma unroll
        for (int q = 0; q < Q_; ++q) {
            const float a = acc[q] * invNqBuf[b * Q_ + q];  // = dot/||q||
            const float wv = (a < -nd)        ? 0.f
                           : (a < -0.5f * nd) ? w10
                           : (a < 0.f)        ? w11
                           : (a < 0.5f * nd)  ? w12
                           : (a < nd)         ? w13
                           : (a <= nd)        ? w14
                                              : 0.f;
            total = fmaf(wqBuf[b * Q_ + q], wv, total);     // uniform s_loads
        }
    }
#pragma unroll
    for (int off = 32; off > 0; off >>= 1) total += __shfl_xor(total, off);
    if ((t & 63) == 0) wsum[t >> 6] = total;
    __syncthreads();
    if (t == 0)
        atomicAdd(&score[b * D_ + d], wsum[0] + wsum[1] + wsum[2] + wsum[3]);
}

extern "C" void kernel_launch(void* const* d_in, const int* in_sizes, int n_in,
                              void* d_out, int out_size, void* d_ws, size_t ws_size,
                              hipStream_t stream)
{
    const int*   bq     = (const int*)d_in[0];
    const int*   bdocs  = (const int*)d_in[1];
    const float* emb    = (const float*)d_in[2];
    const float* gate_w = (const float*)d_in[3];
    const float* gate_b = (const float*)d_in[4];
    const float* w1     = (const float*)d_in[5];
    const float* b1     = (const float*)d_in[6];
    const float* w2     = (const float*)d_in[7];
    const float* b2     = (const float*)d_in[8];
    const float* out_w  = (const float*)d_in[9];
    const float* out_b  = (const float*)d_in[10];

    float* score  = (float*)d_out;
    float* wqBuf  = (float*)d_ws;          // 512 floats
    float* invNq  = wqBuf + B_ * Q_;       // 512 floats  (ws usage: 4 KiB)

    drmm_prep<<<dim3(B_), dim3(256), 0, stream>>>(
        bq, emb, gate_w, gate_b, b1, w2, b2, out_w, out_b, wqBuf, invNq, score);

    drmm_main<<<dim3(4, D_, B_), dim3(256), 0, stream>>>(
        bq, bdocs, emb, w1, wqBuf, invNq, score);
}